// Round 5
// baseline (192.702 us; speedup 1.0000x reference)
//
#include <hip/hip_runtime.h>
#include <hip/hip_bf16.h>

// CfC / liquid-RNN scan on MFMA, R11: split-8 with R9's conflict-free
// transposed buffers and 2 non-draining barriers.
// R10 post-mortem: regression from (1) per-lane zbuf rows -> 12.35M LDS bank
// conflicts (R9 had 0), (2) a 3rd barrier, (3) fetch/write blowup. R11 keeps
// R9's math BITWISE and its [row][lane] LDS idiom, 8 waves, asymmetric roles:
//   waves 0-3: phase1 m-tile w (4 MFMA hi+lo, 4 lecun) -> abuf[2w..2w+1][lane]
//   all 8:     phase2 ONE head tile w (4 MFMA, 6 trans) -> out + h b16-half
//   waves 4-7: x owner: reg ping-pong prefetch (full-step slack) + xbuf stage
// A2 frag kt = abuf rows 4kt..4kt+3 at own lane (stride-free b32 reads).
// h: wave w writes unit ub+w = ushort half (w&1) of hbuf[w>>1][lane] --
// byte-enables merge, no race. 2 BAR_LDS/step, vmcnt NEVER drained in loop.
// 1024 blocks x 512 thr, launch_bounds(512,8) -> target 32 waves/CU from 4
// independent blocks. absmax must be exactly 0.009765625 (tripwire).

#define CIN      16
#define UNITS    32
#define BACKBONE 64
#define CZ       48
#define TSTEPS   32
#define HW       4096
#define NPIX     16
#define NTHREADS 512

typedef __attribute__((ext_vector_type(8))) short  short8;
typedef __attribute__((ext_vector_type(8))) __bf16 bf16x8;
typedef __attribute__((ext_vector_type(4))) float  float4v;
typedef __attribute__((ext_vector_type(4))) unsigned int uint4v;

// LDS-only barrier: drain LDS pipe, sync waves; vmem stays in flight.
#define BAR_LDS() asm volatile("s_waitcnt lgkmcnt(0)\n\ts_barrier" ::: "memory")

__device__ __forceinline__ unsigned short bf16_rne(float f) {
    unsigned u = __float_as_uint(f);
    return (unsigned short)((u + 0x7FFFu + ((u >> 16) & 1u)) >> 16);
}
__device__ __forceinline__ float bf16_tof(unsigned short h) {
    return __uint_as_float(((unsigned)h) << 16);
}
// packed f32x2 -> bf16x2 (RNE), single VALU op
__device__ __forceinline__ unsigned cvt_pk_bf16(float lo, float hi) {
    unsigned r;
    asm("v_cvt_pk_bf16_f32 %0, %1, %2" : "=v"(r) : "v"(lo), "v"(hi));
    return r;
}

#if __has_builtin(__builtin_amdgcn_exp2f)
#define EXP2F(x) __builtin_amdgcn_exp2f(x)
#else
#define EXP2F(x) __expf(0.69314718056f * (x))
#endif
#if __has_builtin(__builtin_amdgcn_rcpf)
#define RCPF(x) __builtin_amdgcn_rcpf(x)
#else
#define RCPF(x) __fdividef(1.0f, (x))
#endif

// 1.7159*tanh(0.666*v) = 1.7159 - 3.4318/(2^(1.332*log2e*v)+1)
__device__ __forceinline__ float lecun_tanh_f(float v) {
    float e = EXP2F(1.92166925f * v);
    return fmaf(-3.4318f, RCPF(e + 1.0f), 1.7159f);
}
__device__ __forceinline__ float tanh_f(float v) {
    float e = EXP2F(2.88539008f * v);
    return fmaf(-2.0f, RCPF(e + 1.0f), 1.0f);
}
__device__ __forceinline__ float sigmoid_f(float v) {
    float e = EXP2F(-1.44269504f * v);
    return RCPF(1.0f + e);
}
__device__ __forceinline__ float4v mfma16(bf16x8 a, bf16x8 b, float4v c) {
    return __builtin_amdgcn_mfma_f32_16x16x32_bf16(a, b, c, 0, 0, 0);
}
__device__ __forceinline__ void split8(const float* v, bf16x8& hi, bf16x8& lo) {
    short8 sh, sl;
    #pragma unroll
    for (int j = 0; j < 8; ++j) {
        unsigned short h = bf16_rne(v[j]);
        sh[j] = (short)h;
        sl[j] = (short)bf16_rne(v[j] - bf16_tof(h));
    }
    hi = __builtin_bit_cast(bf16x8, sh);
    lo = __builtin_bit_cast(bf16x8, sl);
}

__global__ __launch_bounds__(NTHREADS, 8)
void cfc_mfma_kernel(const float* __restrict__ x,   const float* __restrict__ Wb,
                     const float* __restrict__ bb,
                     const float* __restrict__ Wff1, const float* __restrict__ bff1,
                     const float* __restrict__ Wff2, const float* __restrict__ bff2,
                     const float* __restrict__ Wta,  const float* __restrict__ bta,
                     const float* __restrict__ Wtb,  const float* __restrict__ btb,
                     float* __restrict__ out)
{
    // transposed [row][lane] buffers -- all accesses 2-way-or-better (free)
    __shared__ unsigned hbuf[4][64];   // h pairs: dword p = (ub+2p, ub+2p+1)
    __shared__ unsigned abuf[8][64];   // acts: row mt*2+s; A2 frag kt = rows 4kt..4kt+3
    __shared__ unsigned xbuf[8][16];   // x ch-pair r = (2r,2r+1), col = pixel ln

    const int tid  = threadIdx.x;
    const int w    = tid >> 6;          // wave id 0..7
    const int lane = tid & 63;
    const int ln   = lane & 15;         // MFMA m/n (pixel for B/C)
    const int lq   = lane >> 4;         // MFMA quad

    const int gpix = blockIdx.x * NPIX;
    const int b    = gpix >> 12;
    const int pinb = gpix & 4095;

    const int mt = w & 3;               // phase-1 m-tile (waves 0-3)

    // ---- phase-1 A frags: backbone m-tile mt, hi+lo (used by waves 0-3) ---
    bf16x8 A1hi[2], A1lo[2];
    #pragma unroll
    for (int kt = 0; kt < 2; ++kt) {
        float v[8];
        #pragma unroll
        for (int j = 0; j < 8; ++j) {
            int c = kt * 32 + lq * 8 + j;
            v[j] = (c < CZ) ? Wb[(mt * 16 + ln) * CZ + c] : 0.0f;
        }
        split8(v, A1hi[kt], A1lo[kt]);
    }
    float bbias[4];
    #pragma unroll
    for (int r = 0; r < 4; ++r) bbias[r] = bb[mt * 16 + lq * 4 + r];

    // ---- phase-2 A frags: head tile w (one per wave), permuted rows/cols --
    const int head = ln & 3;
    const float* Whp = (head == 0) ? Wff1 : (head == 1) ? Wff2 : (head == 2) ? Wta : Wtb;
    const int urow = (((ln >> 2) + 2) & 3) * 8;
    bf16x8 Ah_hi[2], Ah_lo[2];
    #pragma unroll
    for (int kt = 0; kt < 2; ++kt) {
        float v[8];
        #pragma unroll
        for (int j = 0; j < 8; ++j) {
            int n = 32 * kt + (j >> 2) * 16 + lq * 4 + (j & 3);
            v[j] = Whp[(urow + w) * BACKBONE + n];
        }
        split8(v, Ah_hi[kt], Ah_lo[kt]);
    }
    // gate-side unit of THIS lane: ub + w (head = r in acc regs)
    const int ub = ((lq + 2) & 3) * 8;
    const int u2 = ub + w;
    float hbias[4];
    hbias[0] = bff1[u2]; hbias[1] = bff2[u2];
    hbias[2] = bta[u2];  hbias[3] = btb[u2];

    // ---- x producer params (waves 4-7, lanes lq<2) ------------------------
    const int xr = 2 * (w & 3) + (lq & 1);            // ch-pair row 0..7
    const unsigned xi0 = ((unsigned)(b * CIN + 2 * xr) * TSTEPS) * HW
                         + (unsigned)(pinb + ln);
    const unsigned xi1 = xi0 + (unsigned)(TSTEPS * HW);   // next channel

    // out offset (unit u2, pixel ln)
    const unsigned oo = ((unsigned)(b * UNITS + u2) * TSTEPS) * HW
                        + (unsigned)(pinb + ln);

    // h-publish address: ushort half (w&1) of hbuf[w>>1][lane]
    unsigned short* const hwp =
        (unsigned short*)&hbuf[w >> 1][lane] + (w & 1);

    // ---- prologue: h0 = 0, stage x_0, prefetch x_1 ------------------------
    if (tid < 256) ((unsigned*)hbuf)[tid] = 0u;
    float c0 = 0.f, c1 = 0.f, n0 = 0.f, n1 = 0.f;
    if (w >= 4 && lq < 2) {
        float a0 = x[xi0], a1 = x[xi1];               // x_0
        xbuf[xr][ln] = cvt_pk_bf16(a0, a1);
        c0 = x[xi0 + HW]; c1 = x[xi1 + HW];           // x_1
    }
    __syncthreads();

    unsigned toff = 0;

    auto step = [&](int t, float cx0, float cx1, float& nx0, float& nx1) {
        if (w < 4) {
            // ---- gather h + x (stride-free b32 reads) ----
            unsigned hpk[4], xpk[4];
            #pragma unroll
            for (int p = 0; p < 4; ++p) hpk[p] = hbuf[p][lane];
            #pragma unroll
            for (int p = 0; p < 4; ++p) xpk[p] = xbuf[(lq & 1) * 4 + p][ln];

            // ---- build z fragments (bitwise = R9) ----
            const bool xl = (lq < 2);
            unsigned z0u[4], z1u[4];
            #pragma unroll
            for (int p = 0; p < 4; ++p) {
                z0u[p] = xl ? xpk[p] : hpk[p];
                z1u[p] = xl ? hpk[p] : 0u;   // lq2,3 kt1 = K-pad zeros
            }
            uint4v zv0 = {z0u[0], z0u[1], z0u[2], z0u[3]};
            uint4v zv1 = {z1u[0], z1u[1], z1u[2], z1u[3]};
            bf16x8 Z0 = __builtin_bit_cast(bf16x8, zv0);
            bf16x8 Z1 = __builtin_bit_cast(bf16x8, zv1);

            // ---- phase 1: m-tile mt, hi+lo (4 MFMA, same order as R9) ----
            float4v a = {bbias[0], bbias[1], bbias[2], bbias[3]};
            a = mfma16(A1hi[0], Z0, a);
            a = mfma16(A1lo[0], Z0, a);
            a = mfma16(A1hi[1], Z1, a);
            a = mfma16(A1lo[1], Z1, a);

            // lecun + publish 2 act dwords (rows 2mt, 2mt+1)
            float g0 = lecun_tanh_f(a[0]);
            float g1 = lecun_tanh_f(a[1]);
            float g2 = lecun_tanh_f(a[2]);
            float g3 = lecun_tanh_f(a[3]);
            abuf[mt * 2 + 0][lane] = cvt_pk_bf16(g0, g1);
            abuf[mt * 2 + 1][lane] = cvt_pk_bf16(g2, g3);
        } else {
            // ---- x owner: issue x_{t+2} loads (full-step slack) ----
            const int tl = (t + 2 < TSTEPS) ? t + 2 : TSTEPS - 1;
            if (lq < 2) {
                nx0 = x[xi0 + (unsigned)tl * HW];
                nx1 = x[xi1 + (unsigned)tl * HW];
            }
        }
        BAR_LDS();   // barrier A: acts published; xbuf free to overwrite

        // ---- x owner: stage x_{t+1} (read next at step t+1 top) ----
        if (w >= 4 && lq < 2)
            xbuf[xr][ln] = cvt_pk_bf16(cx0, cx1);

        // ---- assemble A2: frag kt = abuf rows 4kt..4kt+3 at own lane ----
        unsigned f0[4], f1[4];
        #pragma unroll
        for (int d = 0; d < 4; ++d) f0[d] = abuf[d][lane];
        #pragma unroll
        for (int d = 0; d < 4; ++d) f1[d] = abuf[4 + d][lane];
        uint4v w0 = {f0[0], f0[1], f0[2], f0[3]};
        uint4v w1 = {f1[0], f1[1], f1[2], f1[3]};
        bf16x8 A20 = __builtin_bit_cast(bf16x8, w0);
        bf16x8 A21 = __builtin_bit_cast(bf16x8, w1);

        // ---- phase 2: tile w (4 MFMA, same order as R9), gate, store ----
        float4v c = {hbias[0], hbias[1], hbias[2], hbias[3]};
        c = mfma16(Ah_hi[0], A20, c);
        c = mfma16(Ah_lo[0], A20, c);
        c = mfma16(Ah_hi[1], A21, c);
        c = mfma16(Ah_lo[1], A21, c);
        float f1g = tanh_f(c[0]);
        float f2g = tanh_f(c[1]);
        float ti  = sigmoid_f(c[2] + c[3]);
        float h   = fmaf(ti, f2g - f1g, f1g);
        out[oo + toff] = h;                 // async store; never drained
        unsigned hp = cvt_pk_bf16(h, h);    // low ushort = bf16_rne(h)
        *hwp = (unsigned short)hp;          // publish h half-dword
        BAR_LDS();   // barrier B: h + x_{t+1} ready for step t+1
        toff += (unsigned)HW;
    };

    #pragma unroll 1
    for (int t = 0; t < TSTEPS; t += 2) {
        step(t,     c0, c1, n0, n1);        // ping
        step(t + 1, n0, n1, c0, c1);        // pong (static indexing, rule #20)
    }
}

extern "C" void kernel_launch(void* const* d_in, const int* in_sizes, int n_in,
                              void* d_out, int out_size, void* d_ws, size_t ws_size,
                              hipStream_t stream) {
    dim3 grid(4 * HW / NPIX);   // 1024 blocks x 8 waves; target 4 blocks/CU
    cfc_mfma_kernel<<<grid, NTHREADS, 0, stream>>>(
        (const float*)d_in[0], (const float*)d_in[1], (const float*)d_in[2],
        (const float*)d_in[3], (const float*)d_in[4], (const float*)d_in[5],
        (const float*)d_in[6], (const float*)d_in[7], (const float*)d_in[8],
        (const float*)d_in[9], (const float*)d_in[10],
        (float*)d_out);
}

// Round 6
// 168.020 us; speedup vs baseline: 1.1469x; 1.1469x over previous
//
#include <hip/hip_runtime.h>
#include <hip/hip_bf16.h>

// CfC / liquid-RNN scan on MFMA, R12: hoisted x-GEMM + direct-h Z fragment.
// R11 post-mortem: asym roles convoyed (VALUBusy/Mfma DOWN despite 78% occ);
// symmetric R9 (73us) stands. R9's residual = serial chain (2x LDS ~120cy +
// 4-MFMA chain + trans). R12 shortens it:
//  (1) backbone K=48 = x-part (K=16, h-independent) + h-part (K=32).
//      xz_{t+1} = bb + Wx@x_{t+1} computed in step t's phase-2 window (2 MFMA
//      of pipeline filler); recurrent chain: read h -> 2 MFMA -> lecun -> pub.
//  (2) head-row permutation unit=(ln>>2)*8+tile (drop R9's +2 twist) makes
//      the h-GEMM B-frag = hbuf[0..3][lane] VERBATIM: z-build select/merge,
//      x staging, xbuf all vanish.
// x: per-wave direct loads (8/lane, lq<2; 4x wave-dup L1-served), reg
// ping-pong 2 steps ahead; vmcnt NEVER drained in loop. 2 BAR_LDS/step.
// Same quantization points as R9; x-first reassociation -> absmax ~0.0098
// +- few ulp. 1024 blocks x 4 waves, launch_bounds(256,4).

#define CIN      16
#define UNITS    32
#define BACKBONE 64
#define CZ       48
#define TSTEPS   32
#define HW       4096
#define NPIX     16
#define NTHREADS 256

typedef __attribute__((ext_vector_type(8))) short  short8;
typedef __attribute__((ext_vector_type(8))) __bf16 bf16x8;
typedef __attribute__((ext_vector_type(4))) float  float4v;
typedef __attribute__((ext_vector_type(4))) unsigned int uint4v;

// LDS-only barrier: drain LDS pipe, sync waves; vmem stays in flight.
#define BAR_LDS() asm volatile("s_waitcnt lgkmcnt(0)\n\ts_barrier" ::: "memory")

__device__ __forceinline__ unsigned short bf16_rne(float f) {
    unsigned u = __float_as_uint(f);
    return (unsigned short)((u + 0x7FFFu + ((u >> 16) & 1u)) >> 16);
}
__device__ __forceinline__ float bf16_tof(unsigned short h) {
    return __uint_as_float(((unsigned)h) << 16);
}
// packed f32x2 -> bf16x2 (RNE), single VALU op
__device__ __forceinline__ unsigned cvt_pk_bf16(float lo, float hi) {
    unsigned r;
    asm("v_cvt_pk_bf16_f32 %0, %1, %2" : "=v"(r) : "v"(lo), "v"(hi));
    return r;
}

#if __has_builtin(__builtin_amdgcn_exp2f)
#define EXP2F(x) __builtin_amdgcn_exp2f(x)
#else
#define EXP2F(x) __expf(0.69314718056f * (x))
#endif
#if __has_builtin(__builtin_amdgcn_rcpf)
#define RCPF(x) __builtin_amdgcn_rcpf(x)
#else
#define RCPF(x) __fdividef(1.0f, (x))
#endif

// 1.7159*tanh(0.666*v) = 1.7159 - 3.4318/(2^(1.332*log2e*v)+1)
__device__ __forceinline__ float lecun_tanh_f(float v) {
    float e = EXP2F(1.92166925f * v);
    return fmaf(-3.4318f, RCPF(e + 1.0f), 1.7159f);
}
__device__ __forceinline__ float tanh_f(float v) {
    float e = EXP2F(2.88539008f * v);
    return fmaf(-2.0f, RCPF(e + 1.0f), 1.0f);
}
__device__ __forceinline__ float sigmoid_f(float v) {
    float e = EXP2F(-1.44269504f * v);
    return RCPF(1.0f + e);
}
__device__ __forceinline__ float4v mfma16(bf16x8 a, bf16x8 b, float4v c) {
    return __builtin_amdgcn_mfma_f32_16x16x32_bf16(a, b, c, 0, 0, 0);
}
__device__ __forceinline__ void split8(const float* v, bf16x8& hi, bf16x8& lo) {
    short8 sh, sl;
    #pragma unroll
    for (int j = 0; j < 8; ++j) {
        unsigned short h = bf16_rne(v[j]);
        sh[j] = (short)h;
        sl[j] = (short)bf16_rne(v[j] - bf16_tof(h));
    }
    hi = __builtin_bit_cast(bf16x8, sh);
    lo = __builtin_bit_cast(bf16x8, sl);
}

__global__ __launch_bounds__(NTHREADS, 4)
void cfc_mfma_kernel(const float* __restrict__ x,   const float* __restrict__ Wb,
                     const float* __restrict__ bb,
                     const float* __restrict__ Wff1, const float* __restrict__ bff1,
                     const float* __restrict__ Wff2, const float* __restrict__ bff2,
                     const float* __restrict__ Wta,  const float* __restrict__ bta,
                     const float* __restrict__ Wtb,  const float* __restrict__ btb,
                     float* __restrict__ out)
{
    // transposed [row][lane] buffers -- 2-way bank aliasing only (free, m136)
    __shared__ unsigned hbuf[4][64];   // h pairs: dword p = units (lq*8+2p, +1) at lane
    __shared__ unsigned abuf[8][64];   // acts: rows 2mt,2mt+1; A2 frag kt = rows 4kt..4kt+3

    const int tid  = threadIdx.x;
    const int w    = tid >> 6;          // wave id 0..3
    const int lane = tid & 63;
    const int ln   = lane & 15;         // MFMA m/n (pixel for B/C)
    const int lq   = lane >> 4;         // MFMA quad

    const int gpix = blockIdx.x * NPIX;
    const int b    = gpix >> 12;
    const int pinb = gpix & 4095;
    const int mt   = w;                 // phase-1 m-tile

    // ---- Wh A-frags (recurrent, K=32 single tile): k=lq*8+j -> unit, Wb col 16+u
    bf16x8 Whhi, Whlo;
    {
        float v[8];
        #pragma unroll
        for (int j = 0; j < 8; ++j)
            v[j] = Wb[(mt * 16 + ln) * CZ + CIN + lq * 8 + j];
        split8(v, Whhi, Whlo);
    }
    // ---- Wx A-frags (x part, K=16 in a K=32 tile): k=lq*8+j -> ch (lq<2), else 0
    bf16x8 Wxhi, Wxlo;
    {
        float v[8];
        #pragma unroll
        for (int j = 0; j < 8; ++j)
            v[j] = (lq < 2) ? Wb[(mt * 16 + ln) * CZ + lq * 8 + j] : 0.0f;
        split8(v, Wxhi, Wxlo);
    }
    float bbias[4];
    #pragma unroll
    for (int r = 0; r < 4; ++r) bbias[r] = bb[mt * 16 + lq * 4 + r];

    // ---- phase-2 A frags: head tiles 2w+i2; row ln -> unit (ln>>2)*8 + tile,
    //      head ln&3; col n = 32kt + (j>>2)*16 + lq*4 + (j&3) (acts C->B map)
    const int head = ln & 3;
    const float* Whp = (head == 0) ? Wff1 : (head == 1) ? Wff2 : (head == 2) ? Wta : Wtb;
    const int urow = (ln >> 2) * 8;     // NOTE: +2 twist dropped (see hbuf map)
    bf16x8 Ah_hi[2][2], Ah_lo[2][2];
    #pragma unroll
    for (int i2 = 0; i2 < 2; ++i2) {
        #pragma unroll
        for (int kt = 0; kt < 2; ++kt) {
            float v[8];
            #pragma unroll
            for (int j = 0; j < 8; ++j) {
                int n = 32 * kt + (j >> 2) * 16 + lq * 4 + (j & 3);
                v[j] = Whp[(urow + 2 * w + i2) * BACKBONE + n];
            }
            split8(v, Ah_hi[i2][kt], Ah_lo[i2][kt]);
        }
    }
    // gate-side units of THIS lane: lq*8 + 2w + i2 (head = r in acc regs)
    const int ub = lq * 8;
    float hbias[2][4];
    #pragma unroll
    for (int i2 = 0; i2 < 2; ++i2) {
        int u2 = ub + 2 * w + i2;
        hbias[i2][0] = bff1[u2]; hbias[i2][1] = bff2[u2];
        hbias[i2][2] = bta[u2];  hbias[i2][3] = btb[u2];
    }

    // ---- per-lane global offsets ------------------------------------------
    unsigned xo[8];
    #pragma unroll
    for (int j = 0; j < 8; ++j) {
        int ch = (lq < 2) ? (lq * 8 + j) : 0;      // lq>=2 never loads
        xo[j] = ((unsigned)(b * CIN + ch) * TSTEPS) * HW + (unsigned)(pinb + ln);
    }
    unsigned oo[2];
    #pragma unroll
    for (int i2 = 0; i2 < 2; ++i2)
        oo[i2] = ((unsigned)(b * UNITS + ub + 2 * w + i2) * TSTEPS) * HW
                 + (unsigned)(pinb + ln);

    // pack x regs -> B-frag (slot j = ch lq*8+j); lq>=2 lanes: A is zero there
    auto packx = [&](const float (&v)[8]) {
        uint4v u = {cvt_pk_bf16(v[0], v[1]), cvt_pk_bf16(v[2], v[3]),
                    cvt_pk_bf16(v[4], v[5]), cvt_pk_bf16(v[6], v[7])};
        return __builtin_bit_cast(bf16x8, u);
    };

    // ---- prologue: h0=0, x_0 -> xz_0, issue x_1 ---------------------------
    ((unsigned*)hbuf)[tid] = 0u;        // 256 threads cover 256 dwords
    float xv0[8] = {0,0,0,0,0,0,0,0}, xv1[8] = {0,0,0,0,0,0,0,0};
    if (lq < 2) {
        #pragma unroll
        for (int j = 0; j < 8; ++j) xv0[j] = x[xo[j]];
    }
    float4v xzA, xzB;
    {
        bf16x8 X0 = packx(xv0);
        float4v a = {bbias[0], bbias[1], bbias[2], bbias[3]};
        a = mfma16(Wxhi, X0, a);
        a = mfma16(Wxlo, X0, a);
        xzA = a;
    }
    if (lq < 2) {
        #pragma unroll
        for (int j = 0; j < 8; ++j) xv1[j] = x[xo[j] + HW];
    }
    __syncthreads();
    unsigned toff = 0;

    // step t: uses xzc (=xz_t); issues x_{t+2} into xvi; packs xvp (=x_{t+1})
    // into xzn during phase 2 (off the critical path).
    auto step = [&](int t, float4v xzc, float4v& xzn,
                    float (&xvi)[8], float (&xvp)[8]) {
        const int tl = (t + 2 < TSTEPS) ? t + 2 : TSTEPS - 1;
        if (lq < 2) {
            #pragma unroll
            for (int j = 0; j < 8; ++j) xvi[j] = x[xo[j] + (unsigned)tl * HW];
        }

        // ---- phase 1: Z = hbuf verbatim; 2 MFMA; lecun; publish ----
        unsigned h0 = hbuf[0][lane], h1 = hbuf[1][lane];
        unsigned h2 = hbuf[2][lane], h3 = hbuf[3][lane];
        uint4v zv = {h0, h1, h2, h3};
        bf16x8 Z = __builtin_bit_cast(bf16x8, zv);
        float4v a = xzc;
        a = mfma16(Whhi, Z, a);
        a = mfma16(Whlo, Z, a);
        float g0 = lecun_tanh_f(a[0]);
        float g1 = lecun_tanh_f(a[1]);
        float g2 = lecun_tanh_f(a[2]);
        float g3 = lecun_tanh_f(a[3]);
        abuf[mt * 2 + 0][lane] = cvt_pk_bf16(g0, g1);
        abuf[mt * 2 + 1][lane] = cvt_pk_bf16(g2, g3);
        BAR_LDS();                      // barrier A: acts published

        // ---- xz_{t+1}: independent filler under abuf-read latency ----
        {
            bf16x8 X = packx(xvp);
            float4v q = {bbias[0], bbias[1], bbias[2], bbias[3]};
            q = mfma16(Wxhi, X, q);
            q = mfma16(Wxlo, X, q);
            xzn = q;
        }

        // ---- assemble A2: frag kt = abuf rows 4kt..4kt+3 at own lane ----
        unsigned f0[4], f1[4];
        #pragma unroll
        for (int d = 0; d < 4; ++d) f0[d] = abuf[d][lane];
        #pragma unroll
        for (int d = 0; d < 4; ++d) f1[d] = abuf[4 + d][lane];
        uint4v w0 = {f0[0], f0[1], f0[2], f0[3]};
        uint4v w1 = {f1[0], f1[1], f1[2], f1[3]};
        bf16x8 A20 = __builtin_bit_cast(bf16x8, w0);
        bf16x8 A21 = __builtin_bit_cast(bf16x8, w1);

        // ---- phase 2: 2 head tiles (4 MFMA each), gate, store, publish h --
        float hn[2];
        #pragma unroll
        for (int i2 = 0; i2 < 2; ++i2) {
            float4v c = {hbias[i2][0], hbias[i2][1], hbias[i2][2], hbias[i2][3]};
            c = mfma16(Ah_hi[i2][0], A20, c);
            c = mfma16(Ah_lo[i2][0], A20, c);
            c = mfma16(Ah_hi[i2][1], A21, c);
            c = mfma16(Ah_lo[i2][1], A21, c);
            float f1g = tanh_f(c[0]);
            float f2g = tanh_f(c[1]);
            float ti  = sigmoid_f(c[2] + c[3]);
            float h   = fmaf(ti, f2g - f1g, f1g);
            out[oo[i2] + toff] = h;     // async store; never drained in loop
            hn[i2] = h;
        }
        hbuf[w][lane] = cvt_pk_bf16(hn[0], hn[1]);   // units (lq*8+2w, +1)
        BAR_LDS();                      // barrier B: h ready for step t+1
        toff += (unsigned)HW;
    };

    #pragma unroll 1
    for (int t = 0; t < TSTEPS; t += 2) {
        step(t,     xzA, xzB, xv0, xv1);   // ping
        step(t + 1, xzB, xzA, xv1, xv0);   // pong (static indexing, rule #20)
    }
}

extern "C" void kernel_launch(void* const* d_in, const int* in_sizes, int n_in,
                              void* d_out, int out_size, void* d_ws, size_t ws_size,
                              hipStream_t stream) {
    dim3 grid(4 * HW / NPIX);   // 1024 blocks x 4 waves -> 4 blocks/CU
    cfc_mfma_kernel<<<grid, NTHREADS, 0, stream>>>(
        (const float*)d_in[0], (const float*)d_in[1], (const float*)d_in[2],
        (const float*)d_in[3], (const float*)d_in[4], (const float*)d_in[5],
        (const float*)d_in[6], (const float*)d_in[7], (const float*)d_in[8],
        (const float*)d_in[9], (const float*)d_in[10],
        (float*)d_out);
}

// Round 7
// 158.486 us; speedup vs baseline: 1.2159x; 1.0602x over previous
//
#include <hip/hip_runtime.h>
#include <hip/hip_bf16.h>

// CfC / liquid-RNN scan on MFMA, R13: R12's math, 4 pixel-groups per block,
// 256 blocks x 4 waves -> EXACTLY 1 wave/SIMD with 4x in-wave ILP.
// Model fitting R6-R12: step_wall ~= serial_chain x SIMD-contention. 4
// foreign waves/SIMD (R9/R12) inflate every chain segment ~4x (73-81us);
// 1 wave/SIMD with no extra ILP exposes raw latency (R7, 83us). R13 hides
// latency with the wave's OWN independent work: per step, each wave runs 4
// independent group-chains (phase1 x4, then phase2 x4); compiler interleaves.
// Barriers still 2/step, now syncing 4 waves each ALONE on its SIMD ->
// minimal convoy. Per-SIMD issue/step unchanged; contention factor gone.
// Math bitwise-identical to R12 -> absmax exactly 0.009765625 (tripwire).
// VGPR ~250 OK at 1 wave/SIMD (launch_bounds(256,1) -> cap 512).

#define CIN      16
#define UNITS    32
#define BACKBONE 64
#define CZ       48
#define TSTEPS   32
#define HW       4096
#define NG       4           // pixel-groups per block
#define NPIX     64          // NG * 16
#define NTHREADS 256

typedef __attribute__((ext_vector_type(8))) short  short8;
typedef __attribute__((ext_vector_type(8))) __bf16 bf16x8;
typedef __attribute__((ext_vector_type(4))) float  float4v;
typedef __attribute__((ext_vector_type(4))) unsigned int uint4v;

// LDS-only barrier: drain LDS pipe, sync waves; vmem stays in flight.
#define BAR_LDS() asm volatile("s_waitcnt lgkmcnt(0)\n\ts_barrier" ::: "memory")

__device__ __forceinline__ unsigned short bf16_rne(float f) {
    unsigned u = __float_as_uint(f);
    return (unsigned short)((u + 0x7FFFu + ((u >> 16) & 1u)) >> 16);
}
__device__ __forceinline__ float bf16_tof(unsigned short h) {
    return __uint_as_float(((unsigned)h) << 16);
}
// packed f32x2 -> bf16x2 (RNE), single VALU op
__device__ __forceinline__ unsigned cvt_pk_bf16(float lo, float hi) {
    unsigned r;
    asm("v_cvt_pk_bf16_f32 %0, %1, %2" : "=v"(r) : "v"(lo), "v"(hi));
    return r;
}

#if __has_builtin(__builtin_amdgcn_exp2f)
#define EXP2F(x) __builtin_amdgcn_exp2f(x)
#else
#define EXP2F(x) __expf(0.69314718056f * (x))
#endif
#if __has_builtin(__builtin_amdgcn_rcpf)
#define RCPF(x) __builtin_amdgcn_rcpf(x)
#else
#define RCPF(x) __fdividef(1.0f, (x))
#endif

// 1.7159*tanh(0.666*v) = 1.7159 - 3.4318/(2^(1.332*log2e*v)+1)
__device__ __forceinline__ float lecun_tanh_f(float v) {
    float e = EXP2F(1.92166925f * v);
    return fmaf(-3.4318f, RCPF(e + 1.0f), 1.7159f);
}
__device__ __forceinline__ float tanh_f(float v) {
    float e = EXP2F(2.88539008f * v);
    return fmaf(-2.0f, RCPF(e + 1.0f), 1.0f);
}
__device__ __forceinline__ float sigmoid_f(float v) {
    float e = EXP2F(-1.44269504f * v);
    return RCPF(1.0f + e);
}
__device__ __forceinline__ float4v mfma16(bf16x8 a, bf16x8 b, float4v c) {
    return __builtin_amdgcn_mfma_f32_16x16x32_bf16(a, b, c, 0, 0, 0);
}
__device__ __forceinline__ void split8(const float* v, bf16x8& hi, bf16x8& lo) {
    short8 sh, sl;
    #pragma unroll
    for (int j = 0; j < 8; ++j) {
        unsigned short h = bf16_rne(v[j]);
        sh[j] = (short)h;
        sl[j] = (short)bf16_rne(v[j] - bf16_tof(h));
    }
    hi = __builtin_bit_cast(bf16x8, sh);
    lo = __builtin_bit_cast(bf16x8, sl);
}

__global__ __launch_bounds__(NTHREADS, 1)
void cfc_mfma_kernel(const float* __restrict__ x,   const float* __restrict__ Wb,
                     const float* __restrict__ bb,
                     const float* __restrict__ Wff1, const float* __restrict__ bff1,
                     const float* __restrict__ Wff2, const float* __restrict__ bff2,
                     const float* __restrict__ Wta,  const float* __restrict__ bta,
                     const float* __restrict__ Wtb,  const float* __restrict__ btb,
                     float* __restrict__ out)
{
    // transposed [row][lane] buffers per group -- 2-way aliasing only (free)
    __shared__ unsigned hbuf[NG][4][64];   // h pairs: dword p = units (lq*8+2p,+1)
    __shared__ unsigned abuf[NG][8][64];   // acts rows; A2 frag kt = rows 4kt..4kt+3

    const int tid  = threadIdx.x;
    const int w    = tid >> 6;          // wave id 0..3
    const int lane = tid & 63;
    const int ln   = lane & 15;         // MFMA m/n (pixel within group)
    const int lq   = lane >> 4;         // MFMA quad

    const int gpix = blockIdx.x * NPIX;
    const int b    = gpix >> 12;
    const int pinb = gpix & 4095;       // group g covers pinb + g*16 .. +15
    const int mt   = w;                 // phase-1 m-tile

    // ---- Wh A-frags (recurrent K=32): k=lq*8+j -> unit, Wb col 16+k -------
    bf16x8 Whhi, Whlo;
    {
        float v[8];
        #pragma unroll
        for (int j = 0; j < 8; ++j)
            v[j] = Wb[(mt * 16 + ln) * CZ + CIN + lq * 8 + j];
        split8(v, Whhi, Whlo);
    }
    // ---- Wx A-frags (x K=16 in a K=32 tile): k -> ch (lq<2), else 0 -------
    bf16x8 Wxhi, Wxlo;
    {
        float v[8];
        #pragma unroll
        for (int j = 0; j < 8; ++j)
            v[j] = (lq < 2) ? Wb[(mt * 16 + ln) * CZ + lq * 8 + j] : 0.0f;
        split8(v, Wxhi, Wxlo);
    }
    float bbias[4];
    #pragma unroll
    for (int r = 0; r < 4; ++r) bbias[r] = bb[mt * 16 + lq * 4 + r];

    // ---- phase-2 A frags: head tiles 2w+i2; row ln -> unit (ln>>2)*8+tile,
    //      head ln&3; col n = 32kt + (j>>2)*16 + lq*4 + (j&3) ---------------
    const int head = ln & 3;
    const float* Whp = (head == 0) ? Wff1 : (head == 1) ? Wff2 : (head == 2) ? Wta : Wtb;
    const int urow = (ln >> 2) * 8;
    bf16x8 Ah_hi[2][2], Ah_lo[2][2];
    #pragma unroll
    for (int i2 = 0; i2 < 2; ++i2) {
        #pragma unroll
        for (int kt = 0; kt < 2; ++kt) {
            float v[8];
            #pragma unroll
            for (int j = 0; j < 8; ++j) {
                int n = 32 * kt + (j >> 2) * 16 + lq * 4 + (j & 3);
                v[j] = Whp[(urow + 2 * w + i2) * BACKBONE + n];
            }
            split8(v, Ah_hi[i2][kt], Ah_lo[i2][kt]);
        }
    }
    // gate-side units of THIS lane: lq*8 + 2w + i2 (head = r in acc regs)
    const int ub = lq * 8;
    float hbias[2][4];
    #pragma unroll
    for (int i2 = 0; i2 < 2; ++i2) {
        int u2 = ub + 2 * w + i2;
        hbias[i2][0] = bff1[u2]; hbias[i2][1] = bff2[u2];
        hbias[i2][2] = bta[u2];  hbias[i2][3] = btb[u2];
    }

    // ---- per-lane global offsets (group g adds g*16 on the pixel axis) ----
    unsigned xo[8];
    #pragma unroll
    for (int j = 0; j < 8; ++j) {
        int ch = (lq < 2) ? (lq * 8 + j) : 0;      // lq>=2 never loads
        xo[j] = ((unsigned)(b * CIN + ch) * TSTEPS) * HW + (unsigned)(pinb + ln);
    }
    unsigned oo[2];
    #pragma unroll
    for (int i2 = 0; i2 < 2; ++i2)
        oo[i2] = ((unsigned)(b * UNITS + ub + 2 * w + i2) * TSTEPS) * HW
                 + (unsigned)(pinb + ln);

    // pack x regs -> B-frag (slot j = ch lq*8+j)
    auto packx = [&](const float (&v)[8]) {
        uint4v u = {cvt_pk_bf16(v[0], v[1]), cvt_pk_bf16(v[2], v[3]),
                    cvt_pk_bf16(v[4], v[5]), cvt_pk_bf16(v[6], v[7])};
        return __builtin_bit_cast(bf16x8, u);
    };

    // ---- prologue: h0=0, per group: x_0 -> xz_0, issue x_1 ----------------
    #pragma unroll
    for (int i = 0; i < NG; ++i)
        ((unsigned*)hbuf)[tid + i * NTHREADS] = 0u;

    float xva[NG][8], xvb[NG][8];
    float4v xzA[NG], xzB[NG];
    #pragma unroll
    for (int g = 0; g < NG; ++g) {
        #pragma unroll
        for (int j = 0; j < 8; ++j) { xva[g][j] = 0.0f; xvb[g][j] = 0.0f; }
        if (lq < 2) {
            #pragma unroll
            for (int j = 0; j < 8; ++j) xva[g][j] = x[xo[j] + g * 16];
        }
    }
    #pragma unroll
    for (int g = 0; g < NG; ++g) {
        bf16x8 X0 = packx(xva[g]);
        float4v a = {bbias[0], bbias[1], bbias[2], bbias[3]};
        a = mfma16(Wxhi, X0, a);
        a = mfma16(Wxlo, X0, a);
        xzA[g] = a;
    }
    #pragma unroll
    for (int g = 0; g < NG; ++g) {
        if (lq < 2) {
            #pragma unroll
            for (int j = 0; j < 8; ++j) xvb[g][j] = x[xo[j] + g * 16 + HW];
        }
    }
    __syncthreads();
    unsigned toff = 0;

    // step t: uses xzc (=xz_t); issues x_{t+2} into xvi; packs xvp (=x_{t+1})
    // into xzn during phase 2 (off the critical path).
    auto step = [&](int t, float4v (&xzc)[NG], float4v (&xzn)[NG],
                    float (&xvi)[NG][8], float (&xvp)[NG][8]) {
        const int tl = (t + 2 < TSTEPS) ? t + 2 : TSTEPS - 1;
        if (lq < 2) {
            #pragma unroll
            for (int g = 0; g < NG; ++g)
                #pragma unroll
                for (int j = 0; j < 8; ++j)
                    xvi[g][j] = x[xo[j] + g * 16 + (unsigned)tl * HW];
        }

        // ---- phase 1 (all groups, independent chains interleave) ----
        #pragma unroll
        for (int g = 0; g < NG; ++g) {
            unsigned h0 = hbuf[g][0][lane], h1 = hbuf[g][1][lane];
            unsigned h2 = hbuf[g][2][lane], h3 = hbuf[g][3][lane];
            uint4v zv = {h0, h1, h2, h3};
            bf16x8 Z = __builtin_bit_cast(bf16x8, zv);
            float4v a = xzc[g];
            a = mfma16(Whhi, Z, a);
            a = mfma16(Whlo, Z, a);
            float g0 = lecun_tanh_f(a[0]);
            float g1 = lecun_tanh_f(a[1]);
            float g2 = lecun_tanh_f(a[2]);
            float g3 = lecun_tanh_f(a[3]);
            abuf[g][mt * 2 + 0][lane] = cvt_pk_bf16(g0, g1);
            abuf[g][mt * 2 + 1][lane] = cvt_pk_bf16(g2, g3);
        }
        BAR_LDS();                      // barrier A: acts published

        // ---- xz_{t+1}: independent filler under abuf-read latency ----
        #pragma unroll
        for (int g = 0; g < NG; ++g) {
            bf16x8 X = packx(xvp[g]);
            float4v q = {bbias[0], bbias[1], bbias[2], bbias[3]};
            q = mfma16(Wxhi, X, q);
            q = mfma16(Wxlo, X, q);
            xzn[g] = q;
        }

        // ---- phase 2 (all groups) ----
        #pragma unroll
        for (int g = 0; g < NG; ++g) {
            unsigned f0[4], f1[4];
            #pragma unroll
            for (int d = 0; d < 4; ++d) f0[d] = abuf[g][d][lane];
            #pragma unroll
            for (int d = 0; d < 4; ++d) f1[d] = abuf[g][4 + d][lane];
            uint4v w0 = {f0[0], f0[1], f0[2], f0[3]};
            uint4v w1 = {f1[0], f1[1], f1[2], f1[3]};
            bf16x8 A20 = __builtin_bit_cast(bf16x8, w0);
            bf16x8 A21 = __builtin_bit_cast(bf16x8, w1);

            float hn[2];
            #pragma unroll
            for (int i2 = 0; i2 < 2; ++i2) {
                float4v c = {hbias[i2][0], hbias[i2][1], hbias[i2][2], hbias[i2][3]};
                c = mfma16(Ah_hi[i2][0], A20, c);
                c = mfma16(Ah_lo[i2][0], A20, c);
                c = mfma16(Ah_hi[i2][1], A21, c);
                c = mfma16(Ah_lo[i2][1], A21, c);
                float f1g = tanh_f(c[0]);
                float f2g = tanh_f(c[1]);
                float ti  = sigmoid_f(c[2] + c[3]);
                float h   = fmaf(ti, f2g - f1g, f1g);
                out[oo[i2] + g * 16 + toff] = h;   // async; never drained
                hn[i2] = h;
            }
            hbuf[g][w][lane] = cvt_pk_bf16(hn[0], hn[1]);
        }
        BAR_LDS();                      // barrier B: h ready for step t+1
        toff += (unsigned)HW;
    };

    #pragma unroll 1
    for (int t = 0; t < TSTEPS; t += 2) {
        step(t,     xzA, xzB, xva, xvb);   // ping
        step(t + 1, xzB, xzA, xvb, xva);   // pong (static indexing, rule #20)
    }
}

extern "C" void kernel_launch(void* const* d_in, const int* in_sizes, int n_in,
                              void* d_out, int out_size, void* d_ws, size_t ws_size,
                              hipStream_t stream) {
    dim3 grid(4 * HW / NPIX);   // 256 blocks x 4 waves -> 1 wave/SIMD
    cfc_mfma_kernel<<<grid, NTHREADS, 0, stream>>>(
        (const float*)d_in[0], (const float*)d_in[1], (const float*)d_in[2],
        (const float*)d_in[3], (const float*)d_in[4], (const float*)d_in[5],
        (const float*)d_in[6], (const float*)d_in[7], (const float*)d_in[8],
        (const float*)d_in[9], (const float*)d_in[10],
        (float*)d_out);
}

// Round 8
// 150.910 us; speedup vs baseline: 1.2769x; 1.0502x over previous
//
#include <hip/hip_runtime.h>
#include <hip/hip_bf16.h>

// CfC / liquid-RNN scan on MFMA, R14: issue-diet on the R9/R12 chassis.
// Model (fits R6-R13): effective clock ~0.8-1GHz (MfmaUtil & VALUBusy both
// imply it); at 4 waves/SIMD the kernel is ISSUE-bound -> only instruction
// REMOVAL helps. R14 composes three bit-exact cuts:
//  (a) R12 direct-h Z frag: h-GEMM B-operand = hbuf[0..3][lane] verbatim
//      (no z-build selects) -- proven bit-exact in R12.
//  (b) R12 hoisted xz-GEMM: xz_{t+1} = bb + Wx@x_{t+1} as post-barrier filler.
//  (c) NEW x-dedup: R9/R12 loaded+packed the SAME X frag in all 4 waves
//      (8 ld + 4 cvt + 8 addr each). Now wave w (lanes lq<2) owns ch-pair
//      row r=2w+lq: 2 loads + 1 cvt_pk + 1 ds_write -> xbuf[8][16]; consumers
//      read 4 broadcast/2-way ds_b32 -- already packed, packx GONE.
//      Reads before BAR A, publish after BAR A -> no extra barrier, no race.
// 2 non-draining barriers/step (lgkmcnt only); vmcnt never drained in loop.
// All quantization points bitwise = R12 -> absmax exactly 0.009765625.

#define CIN      16
#define UNITS    32
#define BACKBONE 64
#define CZ       48
#define TSTEPS   32
#define HW       4096
#define NPIX     16
#define NTHREADS 256

typedef __attribute__((ext_vector_type(8))) short  short8;
typedef __attribute__((ext_vector_type(8))) __bf16 bf16x8;
typedef __attribute__((ext_vector_type(4))) float  float4v;
typedef __attribute__((ext_vector_type(4))) unsigned int uint4v;

// LDS-only barrier: drain LDS pipe, sync waves; vmem stays in flight.
#define BAR_LDS() asm volatile("s_waitcnt lgkmcnt(0)\n\ts_barrier" ::: "memory")

__device__ __forceinline__ unsigned short bf16_rne(float f) {
    unsigned u = __float_as_uint(f);
    return (unsigned short)((u + 0x7FFFu + ((u >> 16) & 1u)) >> 16);
}
__device__ __forceinline__ float bf16_tof(unsigned short h) {
    return __uint_as_float(((unsigned)h) << 16);
}
// packed f32x2 -> bf16x2 (RNE), single VALU op
__device__ __forceinline__ unsigned cvt_pk_bf16(float lo, float hi) {
    unsigned r;
    asm("v_cvt_pk_bf16_f32 %0, %1, %2" : "=v"(r) : "v"(lo), "v"(hi));
    return r;
}

#if __has_builtin(__builtin_amdgcn_exp2f)
#define EXP2F(x) __builtin_amdgcn_exp2f(x)
#else
#define EXP2F(x) __expf(0.69314718056f * (x))
#endif
#if __has_builtin(__builtin_amdgcn_rcpf)
#define RCPF(x) __builtin_amdgcn_rcpf(x)
#else
#define RCPF(x) __fdividef(1.0f, (x))
#endif

// 1.7159*tanh(0.666*v) = 1.7159 - 3.4318/(2^(1.332*log2e*v)+1)
__device__ __forceinline__ float lecun_tanh_f(float v) {
    float e = EXP2F(1.92166925f * v);
    return fmaf(-3.4318f, RCPF(e + 1.0f), 1.7159f);
}
__device__ __forceinline__ float tanh_f(float v) {
    float e = EXP2F(2.88539008f * v);
    return fmaf(-2.0f, RCPF(e + 1.0f), 1.0f);
}
__device__ __forceinline__ float sigmoid_f(float v) {
    float e = EXP2F(-1.44269504f * v);
    return RCPF(1.0f + e);
}
__device__ __forceinline__ float4v mfma16(bf16x8 a, bf16x8 b, float4v c) {
    return __builtin_amdgcn_mfma_f32_16x16x32_bf16(a, b, c, 0, 0, 0);
}
__device__ __forceinline__ void split8(const float* v, bf16x8& hi, bf16x8& lo) {
    short8 sh, sl;
    #pragma unroll
    for (int j = 0; j < 8; ++j) {
        unsigned short h = bf16_rne(v[j]);
        sh[j] = (short)h;
        sl[j] = (short)bf16_rne(v[j] - bf16_tof(h));
    }
    hi = __builtin_bit_cast(bf16x8, sh);
    lo = __builtin_bit_cast(bf16x8, sl);
}

__global__ __launch_bounds__(NTHREADS, 4)
void cfc_mfma_kernel(const float* __restrict__ x,   const float* __restrict__ Wb,
                     const float* __restrict__ bb,
                     const float* __restrict__ Wff1, const float* __restrict__ bff1,
                     const float* __restrict__ Wff2, const float* __restrict__ bff2,
                     const float* __restrict__ Wta,  const float* __restrict__ bta,
                     const float* __restrict__ Wtb,  const float* __restrict__ btb,
                     float* __restrict__ out)
{
    // transposed [row][lane/px] buffers -- 2-way aliasing / broadcast only
    __shared__ unsigned hbuf[4][64];   // h pairs: dword p = units (lq*8+2p,+1)
    __shared__ unsigned abuf[8][64];   // acts rows; A2 frag kt = rows 4kt..4kt+3
    __shared__ unsigned xbuf[8][16];   // packed x: row r = ch (2r,2r+1), col px

    const int tid  = threadIdx.x;
    const int w    = tid >> 6;          // wave id 0..3
    const int lane = tid & 63;
    const int ln   = lane & 15;         // MFMA m/n (pixel for B/C)
    const int lq   = lane >> 4;         // MFMA quad

    const int gpix = blockIdx.x * NPIX;
    const int b    = gpix >> 12;
    const int pinb = gpix & 4095;
    const int mt   = w;                 // phase-1 m-tile

    // ---- Wh A-frags (recurrent K=32): k=lq*8+j -> unit, Wb col 16+k -------
    bf16x8 Whhi, Whlo;
    {
        float v[8];
        #pragma unroll
        for (int j = 0; j < 8; ++j)
            v[j] = Wb[(mt * 16 + ln) * CZ + CIN + lq * 8 + j];
        split8(v, Whhi, Whlo);
    }
    // ---- Wx A-frags (x K=16 in a K=32 tile): k -> ch (lq<2), else 0 -------
    bf16x8 Wxhi, Wxlo;
    {
        float v[8];
        #pragma unroll
        for (int j = 0; j < 8; ++j)
            v[j] = (lq < 2) ? Wb[(mt * 16 + ln) * CZ + lq * 8 + j] : 0.0f;
        split8(v, Wxhi, Wxlo);
    }
    float bbias[4];
    #pragma unroll
    for (int r = 0; r < 4; ++r) bbias[r] = bb[mt * 16 + lq * 4 + r];

    // ---- phase-2 A frags: head tiles 2w+i2; row ln -> unit (ln>>2)*8+tile,
    //      head ln&3; col n = 32kt + (j>>2)*16 + lq*4 + (j&3) ---------------
    const int head = ln & 3;
    const float* Whp = (head == 0) ? Wff1 : (head == 1) ? Wff2 : (head == 2) ? Wta : Wtb;
    const int urow = (ln >> 2) * 8;
    bf16x8 Ah_hi[2][2], Ah_lo[2][2];
    #pragma unroll
    for (int i2 = 0; i2 < 2; ++i2) {
        #pragma unroll
        for (int kt = 0; kt < 2; ++kt) {
            float v[8];
            #pragma unroll
            for (int j = 0; j < 8; ++j) {
                int n = 32 * kt + (j >> 2) * 16 + lq * 4 + (j & 3);
                v[j] = Whp[(urow + 2 * w + i2) * BACKBONE + n];
            }
            split8(v, Ah_hi[i2][kt], Ah_lo[i2][kt]);
        }
    }
    // gate-side units of THIS lane: lq*8 + 2w + i2 (head = r in acc regs)
    const int ub = lq * 8;
    float hbias[2][4];
    #pragma unroll
    for (int i2 = 0; i2 < 2; ++i2) {
        int u2 = ub + 2 * w + i2;
        hbias[i2][0] = bff1[u2]; hbias[i2][1] = bff2[u2];
        hbias[i2][2] = bta[u2];  hbias[i2][3] = btb[u2];
    }

    // ---- x producer params: row r = 2w+lq (lanes lq<2), ch (2r, 2r+1) -----
    const int  xr  = 2 * w + (lq & 1);
    const bool xpr = (lq < 2);
    const unsigned xi0 = ((unsigned)(b * CIN + 2 * xr) * TSTEPS) * HW
                         + (unsigned)(pinb + ln);
    const unsigned xi1 = xi0 + (unsigned)(TSTEPS * HW);

    // consumer read rows: (lq&1)*4 + jj  (lq>=2 lanes broadcast-dup lq-2)
    const int xrow = (lq & 1) * 4;

    unsigned oo[2];
    #pragma unroll
    for (int i2 = 0; i2 < 2; ++i2)
        oo[i2] = ((unsigned)(b * UNITS + ub + 2 * w + i2) * TSTEPS) * HW
                 + (unsigned)(pinb + ln);

    // X frag from 4 packed xbuf dwords (pairs (8lq+2jj, 8lq+2jj+1) = R12 order)
    auto xfrag = [&](const unsigned (&xf)[4]) {
        uint4v u = {xf[0], xf[1], xf[2], xf[3]};
        return __builtin_bit_cast(bf16x8, u);
    };

    // ---- prologue ----------------------------------------------------------
    ((unsigned*)hbuf)[tid] = 0u;                    // h0 = 0 (256 dwords)
    if (xpr) {
        float a0 = x[xi0], a1 = x[xi1];             // x_0
        xbuf[xr][ln] = cvt_pk_bf16(a0, a1);
    }
    __syncthreads();
    float4v xzA, xzB;
    {
        unsigned xf[4];
        #pragma unroll
        for (int jj = 0; jj < 4; ++jj) xf[jj] = xbuf[xrow + jj][ln];
        bf16x8 X0 = xfrag(xf);
        float4v a = {bbias[0], bbias[1], bbias[2], bbias[3]};
        a = mfma16(Wxhi, X0, a);
        a = mfma16(Wxlo, X0, a);
        xzA = a;                                    // xz_0
    }
    __syncthreads();                                // xbuf reads done
    float pc0 = 0.f, pc1 = 0.f, pn0 = 0.f, pn1 = 0.f;
    if (xpr) {
        float a0 = x[xi0 + HW], a1 = x[xi1 + HW];   // x_1
        xbuf[xr][ln] = cvt_pk_bf16(a0, a1);
        pc0 = x[xi0 + 2u * HW]; pc1 = x[xi1 + 2u * HW];   // x_2 (in flight)
    }
    __syncthreads();                                // xbuf = x_1; loop invariant
    unsigned toff = 0;

    // invariant at step t entry: xbuf = x_{t+1}; pc = x_{t+2}; xzc = xz_t.
    auto step = [&](int t, float4v xzc, float4v& xzn,
                    float& c0, float& c1, float& n0, float& n1) {
        // issue loads of x_{t+3} (consumed at publish point of step t+1)
        const unsigned tl = (unsigned)((t + 3 < TSTEPS) ? t + 3 : TSTEPS - 1);
        if (xpr) { n0 = x[xi0 + tl * HW]; n1 = x[xi1 + tl * HW]; }

        // read x_{t+1} frag (before BAR A; publish happens after BAR A)
        unsigned xf[4];
        #pragma unroll
        for (int jj = 0; jj < 4; ++jj) xf[jj] = xbuf[xrow + jj][ln];

        // ---- phase 1: Z = hbuf verbatim; 2 MFMA; lecun; publish ----
        unsigned h0 = hbuf[0][lane], h1 = hbuf[1][lane];
        unsigned h2 = hbuf[2][lane], h3 = hbuf[3][lane];
        uint4v zv = {h0, h1, h2, h3};
        bf16x8 Z = __builtin_bit_cast(bf16x8, zv);
        float4v a = xzc;
        a = mfma16(Whhi, Z, a);
        a = mfma16(Whlo, Z, a);
        float g0 = lecun_tanh_f(a[0]);
        float g1 = lecun_tanh_f(a[1]);
        float g2 = lecun_tanh_f(a[2]);
        float g3 = lecun_tanh_f(a[3]);
        abuf[mt * 2 + 0][lane] = cvt_pk_bf16(g0, g1);
        abuf[mt * 2 + 1][lane] = cvt_pk_bf16(g2, g3);
        BAR_LDS();                      // barrier A: acts published, x reads done

        // ---- publish x_{t+2} (regs loaded at t-1); compute xz_{t+1} ----
        if (xpr) xbuf[xr][ln] = cvt_pk_bf16(c0, c1);
        {
            bf16x8 X = xfrag(xf);
            float4v q = {bbias[0], bbias[1], bbias[2], bbias[3]};
            q = mfma16(Wxhi, X, q);
            q = mfma16(Wxlo, X, q);
            xzn = q;
        }

        // ---- assemble A2: frag kt = abuf rows 4kt..4kt+3 at own lane ----
        unsigned f0[4], f1[4];
        #pragma unroll
        for (int d = 0; d < 4; ++d) f0[d] = abuf[d][lane];
        #pragma unroll
        for (int d = 0; d < 4; ++d) f1[d] = abuf[4 + d][lane];
        uint4v w0 = {f0[0], f0[1], f0[2], f0[3]};
        uint4v w1 = {f1[0], f1[1], f1[2], f1[3]};
        bf16x8 A20 = __builtin_bit_cast(bf16x8, w0);
        bf16x8 A21 = __builtin_bit_cast(bf16x8, w1);

        // ---- phase 2: 2 head tiles (4 MFMA each), gate, store, publish h --
        float hn[2];
        #pragma unroll
        for (int i2 = 0; i2 < 2; ++i2) {
            float4v c = {hbias[i2][0], hbias[i2][1], hbias[i2][2], hbias[i2][3]};
            c = mfma16(Ah_hi[i2][0], A20, c);
            c = mfma16(Ah_lo[i2][0], A20, c);
            c = mfma16(Ah_hi[i2][1], A21, c);
            c = mfma16(Ah_lo[i2][1], A21, c);
            float f1g = tanh_f(c[0]);
            float f2g = tanh_f(c[1]);
            float ti  = sigmoid_f(c[2] + c[3]);
            float h   = fmaf(ti, f2g - f1g, f1g);
            out[oo[i2] + toff] = h;     // async store; never drained in loop
            hn[i2] = h;
        }
        hbuf[w][lane] = cvt_pk_bf16(hn[0], hn[1]);   // units (lq*8+2w, +1)
        BAR_LDS();                      // barrier B: h + x_{t+2} ready
        toff += (unsigned)HW;
    };

    #pragma unroll 1
    for (int t = 0; t < TSTEPS; t += 2) {
        step(t,     xzA, xzB, pc0, pc1, pn0, pn1);   // ping
        step(t + 1, xzB, xzA, pn0, pn1, pc0, pc1);   // pong (static, rule #20)
    }
}

extern "C" void kernel_launch(void* const* d_in, const int* in_sizes, int n_in,
                              void* d_out, int out_size, void* d_ws, size_t ws_size,
                              hipStream_t stream) {
    dim3 grid(4 * HW / NPIX);   // 1024 blocks x 4 waves -> 4 blocks/CU
    cfc_mfma_kernel<<<grid, NTHREADS, 0, stream>>>(
        (const float*)d_in[0], (const float*)d_in[1], (const float*)d_in[2],
        (const float*)d_in[3], (const float*)d_in[4], (const float*)d_in[5],
        (const float*)d_in[6], (const float*)d_in[7], (const float*)d_in[8],
        (const float*)d_in[9], (const float*)d_in[10],
        (float*)d_out);
}

// Round 9
// 146.577 us; speedup vs baseline: 1.3147x; 1.0296x over previous
//
#include <hip/hip_runtime.h>
#include <hip/hip_bf16.h>

// CfC / liquid-RNN scan on MFMA, R15 = R14 + block phase-STAGGER.
// R14 post-mortem: issue-diet worked (65us, FETCH at input-minimum), but
// step wall ~4900cy vs ~1200cy issued/SIMD and ~700cy chain -> ~70% dead.
// Diagnosis: the 4 co-resident blocks/CU are PHASE-LOCKED -- launched
// together, identical period, never interact -> each SIMD's 4 waves (from 4
// different blocks) all park at the same barrier at the same time. The
// latency-fill that 4 waves/SIMD should give is structurally disabled.
// R15: at entry, sleep each block by phase * quarter-step (~1200cy);
// phase = ((bid>>8)+bid)&3 gives distinct 0..3 for co-resident sets under
// both round-robin ({m,m+256,m+512,m+768}) and consecutive assignment.
// Offsets persist (identical period). Everything after the sleep is
// bitwise identical to R14 -> absmax must be exactly 0.009765625.

#define CIN      16
#define UNITS    32
#define BACKBONE 64
#define CZ       48
#define TSTEPS   32
#define HW       4096
#define NPIX     16
#define NTHREADS 256

typedef __attribute__((ext_vector_type(8))) short  short8;
typedef __attribute__((ext_vector_type(8))) __bf16 bf16x8;
typedef __attribute__((ext_vector_type(4))) float  float4v;
typedef __attribute__((ext_vector_type(4))) unsigned int uint4v;

// LDS-only barrier: drain LDS pipe, sync waves; vmem stays in flight.
#define BAR_LDS() asm volatile("s_waitcnt lgkmcnt(0)\n\ts_barrier" ::: "memory")

__device__ __forceinline__ unsigned short bf16_rne(float f) {
    unsigned u = __float_as_uint(f);
    return (unsigned short)((u + 0x7FFFu + ((u >> 16) & 1u)) >> 16);
}
__device__ __forceinline__ float bf16_tof(unsigned short h) {
    return __uint_as_float(((unsigned)h) << 16);
}
// packed f32x2 -> bf16x2 (RNE), single VALU op
__device__ __forceinline__ unsigned cvt_pk_bf16(float lo, float hi) {
    unsigned r;
    asm("v_cvt_pk_bf16_f32 %0, %1, %2" : "=v"(r) : "v"(lo), "v"(hi));
    return r;
}

#if __has_builtin(__builtin_amdgcn_exp2f)
#define EXP2F(x) __builtin_amdgcn_exp2f(x)
#else
#define EXP2F(x) __expf(0.69314718056f * (x))
#endif
#if __has_builtin(__builtin_amdgcn_rcpf)
#define RCPF(x) __builtin_amdgcn_rcpf(x)
#else
#define RCPF(x) __fdividef(1.0f, (x))
#endif

// 1.7159*tanh(0.666*v) = 1.7159 - 3.4318/(2^(1.332*log2e*v)+1)
__device__ __forceinline__ float lecun_tanh_f(float v) {
    float e = EXP2F(1.92166925f * v);
    return fmaf(-3.4318f, RCPF(e + 1.0f), 1.7159f);
}
__device__ __forceinline__ float tanh_f(float v) {
    float e = EXP2F(2.88539008f * v);
    return fmaf(-2.0f, RCPF(e + 1.0f), 1.0f);
}
__device__ __forceinline__ float sigmoid_f(float v) {
    float e = EXP2F(-1.44269504f * v);
    return RCPF(1.0f + e);
}
__device__ __forceinline__ float4v mfma16(bf16x8 a, bf16x8 b, float4v c) {
    return __builtin_amdgcn_mfma_f32_16x16x32_bf16(a, b, c, 0, 0, 0);
}
__device__ __forceinline__ void split8(const float* v, bf16x8& hi, bf16x8& lo) {
    short8 sh, sl;
    #pragma unroll
    for (int j = 0; j < 8; ++j) {
        unsigned short h = bf16_rne(v[j]);
        sh[j] = (short)h;
        sl[j] = (short)bf16_rne(v[j] - bf16_tof(h));
    }
    hi = __builtin_bit_cast(bf16x8, sh);
    lo = __builtin_bit_cast(bf16x8, sl);
}

__global__ __launch_bounds__(NTHREADS, 4)
void cfc_mfma_kernel(const float* __restrict__ x,   const float* __restrict__ Wb,
                     const float* __restrict__ bb,
                     const float* __restrict__ Wff1, const float* __restrict__ bff1,
                     const float* __restrict__ Wff2, const float* __restrict__ bff2,
                     const float* __restrict__ Wta,  const float* __restrict__ bta,
                     const float* __restrict__ Wtb,  const float* __restrict__ btb,
                     float* __restrict__ out)
{
    // ---- phase stagger: desync co-resident blocks by ~quarter-step --------
    {
        const int ph = (((int)blockIdx.x >> 8) + (int)blockIdx.x) & 3;
        if      (ph == 1) __builtin_amdgcn_s_sleep(19);   // ~1200 cy
        else if (ph == 2) __builtin_amdgcn_s_sleep(38);   // ~2400 cy
        else if (ph == 3) __builtin_amdgcn_s_sleep(57);   // ~3600 cy
    }

    // transposed [row][lane/px] buffers -- 2-way aliasing / broadcast only
    __shared__ unsigned hbuf[4][64];   // h pairs: dword p = units (lq*8+2p,+1)
    __shared__ unsigned abuf[8][64];   // acts rows; A2 frag kt = rows 4kt..4kt+3
    __shared__ unsigned xbuf[8][16];   // packed x: row r = ch (2r,2r+1), col px

    const int tid  = threadIdx.x;
    const int w    = tid >> 6;          // wave id 0..3
    const int lane = tid & 63;
    const int ln   = lane & 15;         // MFMA m/n (pixel for B/C)
    const int lq   = lane >> 4;         // MFMA quad

    const int gpix = blockIdx.x * NPIX;
    const int b    = gpix >> 12;
    const int pinb = gpix & 4095;
    const int mt   = w;                 // phase-1 m-tile

    // ---- Wh A-frags (recurrent K=32): k=lq*8+j -> unit, Wb col 16+k -------
    bf16x8 Whhi, Whlo;
    {
        float v[8];
        #pragma unroll
        for (int j = 0; j < 8; ++j)
            v[j] = Wb[(mt * 16 + ln) * CZ + CIN + lq * 8 + j];
        split8(v, Whhi, Whlo);
    }
    // ---- Wx A-frags (x K=16 in a K=32 tile): k -> ch (lq<2), else 0 -------
    bf16x8 Wxhi, Wxlo;
    {
        float v[8];
        #pragma unroll
        for (int j = 0; j < 8; ++j)
            v[j] = (lq < 2) ? Wb[(mt * 16 + ln) * CZ + lq * 8 + j] : 0.0f;
        split8(v, Wxhi, Wxlo);
    }
    float bbias[4];
    #pragma unroll
    for (int r = 0; r < 4; ++r) bbias[r] = bb[mt * 16 + lq * 4 + r];

    // ---- phase-2 A frags: head tiles 2w+i2; row ln -> unit (ln>>2)*8+tile,
    //      head ln&3; col n = 32kt + (j>>2)*16 + lq*4 + (j&3) ---------------
    const int head = ln & 3;
    const float* Whp = (head == 0) ? Wff1 : (head == 1) ? Wff2 : (head == 2) ? Wta : Wtb;
    const int urow = (ln >> 2) * 8;
    bf16x8 Ah_hi[2][2], Ah_lo[2][2];
    #pragma unroll
    for (int i2 = 0; i2 < 2; ++i2) {
        #pragma unroll
        for (int kt = 0; kt < 2; ++kt) {
            float v[8];
            #pragma unroll
            for (int j = 0; j < 8; ++j) {
                int n = 32 * kt + (j >> 2) * 16 + lq * 4 + (j & 3);
                v[j] = Whp[(urow + 2 * w + i2) * BACKBONE + n];
            }
            split8(v, Ah_hi[i2][kt], Ah_lo[i2][kt]);
        }
    }
    // gate-side units of THIS lane: lq*8 + 2w + i2 (head = r in acc regs)
    const int ub = lq * 8;
    float hbias[2][4];
    #pragma unroll
    for (int i2 = 0; i2 < 2; ++i2) {
        int u2 = ub + 2 * w + i2;
        hbias[i2][0] = bff1[u2]; hbias[i2][1] = bff2[u2];
        hbias[i2][2] = bta[u2];  hbias[i2][3] = btb[u2];
    }

    // ---- x producer params: row r = 2w+lq (lanes lq<2), ch (2r, 2r+1) -----
    const int  xr  = 2 * w + (lq & 1);
    const bool xpr = (lq < 2);
    const unsigned xi0 = ((unsigned)(b * CIN + 2 * xr) * TSTEPS) * HW
                         + (unsigned)(pinb + ln);
    const unsigned xi1 = xi0 + (unsigned)(TSTEPS * HW);

    // consumer read rows: (lq&1)*4 + jj  (lq>=2 lanes broadcast-dup lq-2)
    const int xrow = (lq & 1) * 4;

    unsigned oo[2];
    #pragma unroll
    for (int i2 = 0; i2 < 2; ++i2)
        oo[i2] = ((unsigned)(b * UNITS + ub + 2 * w + i2) * TSTEPS) * HW
                 + (unsigned)(pinb + ln);

    // X frag from 4 packed xbuf dwords (pairs (8lq+2jj, 8lq+2jj+1) = R12 order)
    auto xfrag = [&](const unsigned (&xf)[4]) {
        uint4v u = {xf[0], xf[1], xf[2], xf[3]};
        return __builtin_bit_cast(bf16x8, u);
    };

    // ---- prologue ----------------------------------------------------------
    ((unsigned*)hbuf)[tid] = 0u;                    // h0 = 0 (256 dwords)
    if (xpr) {
        float a0 = x[xi0], a1 = x[xi1];             // x_0
        xbuf[xr][ln] = cvt_pk_bf16(a0, a1);
    }
    __syncthreads();
    float4v xzA, xzB;
    {
        unsigned xf[4];
        #pragma unroll
        for (int jj = 0; jj < 4; ++jj) xf[jj] = xbuf[xrow + jj][ln];
        bf16x8 X0 = xfrag(xf);
        float4v a = {bbias[0], bbias[1], bbias[2], bbias[3]};
        a = mfma16(Wxhi, X0, a);
        a = mfma16(Wxlo, X0, a);
        xzA = a;                                    // xz_0
    }
    __syncthreads();                                // xbuf reads done
    float pc0 = 0.f, pc1 = 0.f, pn0 = 0.f, pn1 = 0.f;
    if (xpr) {
        float a0 = x[xi0 + HW], a1 = x[xi1 + HW];   // x_1
        xbuf[xr][ln] = cvt_pk_bf16(a0, a1);
        pc0 = x[xi0 + 2u * HW]; pc1 = x[xi1 + 2u * HW];   // x_2 (in flight)
    }
    __syncthreads();                                // xbuf = x_1; loop invariant
    unsigned toff = 0;

    // invariant at step t entry: xbuf = x_{t+1}; pc = x_{t+2}; xzc = xz_t.
    auto step = [&](int t, float4v xzc, float4v& xzn,
                    float& c0, float& c1, float& n0, float& n1) {
        // issue loads of x_{t+3} (consumed at publish point of step t+1)
        const unsigned tl = (unsigned)((t + 3 < TSTEPS) ? t + 3 : TSTEPS - 1);
        if (xpr) { n0 = x[xi0 + tl * HW]; n1 = x[xi1 + tl * HW]; }

        // read x_{t+1} frag (before BAR A; publish happens after BAR A)
        unsigned xf[4];
        #pragma unroll
        for (int jj = 0; jj < 4; ++jj) xf[jj] = xbuf[xrow + jj][ln];

        // ---- phase 1: Z = hbuf verbatim; 2 MFMA; lecun; publish ----
        unsigned h0 = hbuf[0][lane], h1 = hbuf[1][lane];
        unsigned h2 = hbuf[2][lane], h3 = hbuf[3][lane];
        uint4v zv = {h0, h1, h2, h3};
        bf16x8 Z = __builtin_bit_cast(bf16x8, zv);
        float4v a = xzc;
        a = mfma16(Whhi, Z, a);
        a = mfma16(Whlo, Z, a);
        float g0 = lecun_tanh_f(a[0]);
        float g1 = lecun_tanh_f(a[1]);
        float g2 = lecun_tanh_f(a[2]);
        float g3 = lecun_tanh_f(a[3]);
        abuf[mt * 2 + 0][lane] = cvt_pk_bf16(g0, g1);
        abuf[mt * 2 + 1][lane] = cvt_pk_bf16(g2, g3);
        BAR_LDS();                      // barrier A: acts published, x reads done

        // ---- publish x_{t+2} (regs loaded at t-1); compute xz_{t+1} ----
        if (xpr) xbuf[xr][ln] = cvt_pk_bf16(c0, c1);
        {
            bf16x8 X = xfrag(xf);
            float4v q = {bbias[0], bbias[1], bbias[2], bbias[3]};
            q = mfma16(Wxhi, X, q);
            q = mfma16(Wxlo, X, q);
            xzn = q;
        }

        // ---- assemble A2: frag kt = abuf rows 4kt..4kt+3 at own lane ----
        unsigned f0[4], f1[4];
        #pragma unroll
        for (int d = 0; d < 4; ++d) f0[d] = abuf[d][lane];
        #pragma unroll
        for (int d = 0; d < 4; ++d) f1[d] = abuf[4 + d][lane];
        uint4v w0 = {f0[0], f0[1], f0[2], f0[3]};
        uint4v w1 = {f1[0], f1[1], f1[2], f1[3]};
        bf16x8 A20 = __builtin_bit_cast(bf16x8, w0);
        bf16x8 A21 = __builtin_bit_cast(bf16x8, w1);

        // ---- phase 2: 2 head tiles (4 MFMA each), gate, store, publish h --
        float hn[2];
        #pragma unroll
        for (int i2 = 0; i2 < 2; ++i2) {
            float4v c = {hbias[i2][0], hbias[i2][1], hbias[i2][2], hbias[i2][3]};
            c = mfma16(Ah_hi[i2][0], A20, c);
            c = mfma16(Ah_lo[i2][0], A20, c);
            c = mfma16(Ah_hi[i2][1], A21, c);
            c = mfma16(Ah_lo[i2][1], A21, c);
            float f1g = tanh_f(c[0]);
            float f2g = tanh_f(c[1]);
            float ti  = sigmoid_f(c[2] + c[3]);
            float h   = fmaf(ti, f2g - f1g, f1g);
            out[oo[i2] + toff] = h;     // async store; never drained in loop
            hn[i2] = h;
        }
        hbuf[w][lane] = cvt_pk_bf16(hn[0], hn[1]);   // units (lq*8+2w, +1)
        BAR_LDS();                      // barrier B: h + x_{t+2} ready
        toff += (unsigned)HW;
    };

    #pragma unroll 1
    for (int t = 0; t < TSTEPS; t += 2) {
        step(t,     xzA, xzB, pc0, pc1, pn0, pn1);   // ping
        step(t + 1, xzB, xzA, pn0, pn1, pc0, pc1);   // pong (static, rule #20)
    }
}

extern "C" void kernel_launch(void* const* d_in, const int* in_sizes, int n_in,
                              void* d_out, int out_size, void* d_ws, size_t ws_size,
                              hipStream_t stream) {
    dim3 grid(4 * HW / NPIX);   // 1024 blocks x 4 waves -> 4 blocks/CU
    cfc_mfma_kernel<<<grid, NTHREADS, 0, stream>>>(
        (const float*)d_in[0], (const float*)d_in[1], (const float*)d_in[2],
        (const float*)d_in[3], (const float*)d_in[4], (const float*)d_in[5],
        (const float*)d_in[6], (const float*)d_in[7], (const float*)d_in[8],
        (const float*)d_in[9], (const float*)d_in[10],
        (float*)d_out);
}

// Round 10
// 146.006 us; speedup vs baseline: 1.3198x; 1.0039x over previous
//
#include <hip/hip_runtime.h>
#include <hip/hip_bf16.h>

// CfC / liquid-RNN scan on MFMA, R16: deeper issue/chain diet on R14.
// R15 post-mortem: stagger = pure overhead (+sleep, no util change) ->
// blocks already desynced; phase-lock theory dead. R7 recheck: the big
// stall exists even with ZERO barriers/LDS -> not sync-fixable. Empirical
// law across R6-R15: only instruction REMOVAL and chain SHORTENING help.
// R16 cuts, on the R14 chassis:
//  (1) head weights hi-ONLY (phase2 8->4 MFMA, chain 4->2, -16 VGPR).
//      Backbone Wh/Wx keep hi+lo (recurrent-Jacobian path stays precise);
//      head rounding error enters h additively, damped by the contractive
//      map. Predicted absmax ~0.012-0.016 (R6 analysis: threshold ~0.02).
//  (2) persistent bias float4v passed as MFMA C-in (xz + 2 head tiles):
//      kills ~12 acc-init movs/step.
//  (3) T5 setprio: prio1 on the recurrent chain, prio0 around filler
//      (x publish + xz) -- desynced-block regime matches attn's +4-7%.
// Everything else bitwise = R14. vmcnt never drained in loop; 2 BAR_LDS.

#define CIN      16
#define UNITS    32
#define BACKBONE 64
#define CZ       48
#define TSTEPS   32
#define HW       4096
#define NPIX     16
#define NTHREADS 256

typedef __attribute__((ext_vector_type(8))) short  short8;
typedef __attribute__((ext_vector_type(8))) __bf16 bf16x8;
typedef __attribute__((ext_vector_type(4))) float  float4v;
typedef __attribute__((ext_vector_type(4))) unsigned int uint4v;

// LDS-only barrier: drain LDS pipe, sync waves; vmem stays in flight.
#define BAR_LDS() asm volatile("s_waitcnt lgkmcnt(0)\n\ts_barrier" ::: "memory")

__device__ __forceinline__ unsigned short bf16_rne(float f) {
    unsigned u = __float_as_uint(f);
    return (unsigned short)((u + 0x7FFFu + ((u >> 16) & 1u)) >> 16);
}
__device__ __forceinline__ float bf16_tof(unsigned short h) {
    return __uint_as_float(((unsigned)h) << 16);
}
// packed f32x2 -> bf16x2 (RNE), single VALU op
__device__ __forceinline__ unsigned cvt_pk_bf16(float lo, float hi) {
    unsigned r;
    asm("v_cvt_pk_bf16_f32 %0, %1, %2" : "=v"(r) : "v"(lo), "v"(hi));
    return r;
}

#if __has_builtin(__builtin_amdgcn_exp2f)
#define EXP2F(x) __builtin_amdgcn_exp2f(x)
#else
#define EXP2F(x) __expf(0.69314718056f * (x))
#endif
#if __has_builtin(__builtin_amdgcn_rcpf)
#define RCPF(x) __builtin_amdgcn_rcpf(x)
#else
#define RCPF(x) __fdividef(1.0f, (x))
#endif

// 1.7159*tanh(0.666*v) = 1.7159 - 3.4318/(2^(1.332*log2e*v)+1)
__device__ __forceinline__ float lecun_tanh_f(float v) {
    float e = EXP2F(1.92166925f * v);
    return fmaf(-3.4318f, RCPF(e + 1.0f), 1.7159f);
}
__device__ __forceinline__ float tanh_f(float v) {
    float e = EXP2F(2.88539008f * v);
    return fmaf(-2.0f, RCPF(e + 1.0f), 1.0f);
}
__device__ __forceinline__ float sigmoid_f(float v) {
    float e = EXP2F(-1.44269504f * v);
    return RCPF(1.0f + e);
}
__device__ __forceinline__ float4v mfma16(bf16x8 a, bf16x8 b, float4v c) {
    return __builtin_amdgcn_mfma_f32_16x16x32_bf16(a, b, c, 0, 0, 0);
}
__device__ __forceinline__ void split8(const float* v, bf16x8& hi, bf16x8& lo) {
    short8 sh, sl;
    #pragma unroll
    for (int j = 0; j < 8; ++j) {
        unsigned short h = bf16_rne(v[j]);
        sh[j] = (short)h;
        sl[j] = (short)bf16_rne(v[j] - bf16_tof(h));
    }
    hi = __builtin_bit_cast(bf16x8, sh);
    lo = __builtin_bit_cast(bf16x8, sl);
}
__device__ __forceinline__ bf16x8 pack8hi(const float* v) {
    short8 sh;
    #pragma unroll
    for (int j = 0; j < 8; ++j) sh[j] = (short)bf16_rne(v[j]);
    return __builtin_bit_cast(bf16x8, sh);
}

__global__ __launch_bounds__(NTHREADS, 4)
void cfc_mfma_kernel(const float* __restrict__ x,   const float* __restrict__ Wb,
                     const float* __restrict__ bb,
                     const float* __restrict__ Wff1, const float* __restrict__ bff1,
                     const float* __restrict__ Wff2, const float* __restrict__ bff2,
                     const float* __restrict__ Wta,  const float* __restrict__ bta,
                     const float* __restrict__ Wtb,  const float* __restrict__ btb,
                     float* __restrict__ out)
{
    // transposed [row][lane/px] buffers -- 2-way aliasing / broadcast only
    __shared__ unsigned hbuf[4][64];   // h pairs: dword p = units (lq*8+2p,+1)
    __shared__ unsigned abuf[8][64];   // acts rows; A2 frag kt = rows 4kt..4kt+3
    __shared__ unsigned xbuf[8][16];   // packed x: row r = ch (2r,2r+1), col px

    const int tid  = threadIdx.x;
    const int w    = tid >> 6;          // wave id 0..3
    const int lane = tid & 63;
    const int ln   = lane & 15;         // MFMA m/n (pixel for B/C)
    const int lq   = lane >> 4;         // MFMA quad

    const int gpix = blockIdx.x * NPIX;
    const int b    = gpix >> 12;
    const int pinb = gpix & 4095;
    const int mt   = w;                 // phase-1 m-tile

    // ---- Wh A-frags (recurrent K=32): k=lq*8+j -> unit, Wb col 16+k -------
    bf16x8 Whhi, Whlo;
    {
        float v[8];
        #pragma unroll
        for (int j = 0; j < 8; ++j)
            v[j] = Wb[(mt * 16 + ln) * CZ + CIN + lq * 8 + j];
        split8(v, Whhi, Whlo);
    }
    // ---- Wx A-frags (x K=16 in a K=32 tile): k -> ch (lq<2), else 0 -------
    bf16x8 Wxhi, Wxlo;
    {
        float v[8];
        #pragma unroll
        for (int j = 0; j < 8; ++j)
            v[j] = (lq < 2) ? Wb[(mt * 16 + ln) * CZ + lq * 8 + j] : 0.0f;
        split8(v, Wxhi, Wxlo);
    }
    // backbone bias as persistent C-in vector
    float4v BBv;
    #pragma unroll
    for (int r = 0; r < 4; ++r) BBv[r] = bb[mt * 16 + lq * 4 + r];

    // ---- phase-2 A frags: head tiles 2w+i2, HI ONLY (R16 cut (1)) ---------
    //      row ln -> unit (ln>>2)*8+tile, head ln&3;
    //      col n = 32kt + (j>>2)*16 + lq*4 + (j&3)
    const int head = ln & 3;
    const float* Whp = (head == 0) ? Wff1 : (head == 1) ? Wff2 : (head == 2) ? Wta : Wtb;
    const int urow = (ln >> 2) * 8;
    bf16x8 Ah[2][2];
    #pragma unroll
    for (int i2 = 0; i2 < 2; ++i2) {
        #pragma unroll
        for (int kt = 0; kt < 2; ++kt) {
            float v[8];
            #pragma unroll
            for (int j = 0; j < 8; ++j) {
                int n = 32 * kt + (j >> 2) * 16 + lq * 4 + (j & 3);
                v[j] = Whp[(urow + 2 * w + i2) * BACKBONE + n];
            }
            Ah[i2][kt] = pack8hi(v);
        }
    }
    // gate-side units of THIS lane: lq*8 + 2w + i2; bias as C-in vectors
    const int ub = lq * 8;
    float4v HBv[2];
    #pragma unroll
    for (int i2 = 0; i2 < 2; ++i2) {
        int u2 = ub + 2 * w + i2;
        HBv[i2][0] = bff1[u2]; HBv[i2][1] = bff2[u2];
        HBv[i2][2] = bta[u2];  HBv[i2][3] = btb[u2];
    }

    // ---- x producer params: row r = 2w+lq (lanes lq<2), ch (2r, 2r+1) -----
    const int  xr  = 2 * w + (lq & 1);
    const bool xpr = (lq < 2);
    const unsigned xi0 = ((unsigned)(b * CIN + 2 * xr) * TSTEPS) * HW
                         + (unsigned)(pinb + ln);
    const unsigned xi1 = xi0 + (unsigned)(TSTEPS * HW);

    // consumer read rows: (lq&1)*4 + jj  (lq>=2 lanes broadcast-dup lq-2)
    const int xrow = (lq & 1) * 4;

    unsigned oo[2];
    #pragma unroll
    for (int i2 = 0; i2 < 2; ++i2)
        oo[i2] = ((unsigned)(b * UNITS + ub + 2 * w + i2) * TSTEPS) * HW
                 + (unsigned)(pinb + ln);

    // X frag from 4 packed xbuf dwords (pairs (8lq+2jj, 8lq+2jj+1))
    auto xfrag = [&](const unsigned (&xf)[4]) {
        uint4v u = {xf[0], xf[1], xf[2], xf[3]};
        return __builtin_bit_cast(bf16x8, u);
    };

    // ---- prologue ----------------------------------------------------------
    ((unsigned*)hbuf)[tid] = 0u;                    // h0 = 0 (256 dwords)
    if (xpr) {
        float a0 = x[xi0], a1 = x[xi1];             // x_0
        xbuf[xr][ln] = cvt_pk_bf16(a0, a1);
    }
    __syncthreads();
    float4v xzA, xzB;
    {
        unsigned xf[4];
        #pragma unroll
        for (int jj = 0; jj < 4; ++jj) xf[jj] = xbuf[xrow + jj][ln];
        bf16x8 X0 = xfrag(xf);
        float4v a = mfma16(Wxhi, X0, BBv);
        a = mfma16(Wxlo, X0, a);
        xzA = a;                                    // xz_0
    }
    __syncthreads();                                // xbuf reads done
    float pc0 = 0.f, pc1 = 0.f, pn0 = 0.f, pn1 = 0.f;
    if (xpr) {
        float a0 = x[xi0 + HW], a1 = x[xi1 + HW];   // x_1
        xbuf[xr][ln] = cvt_pk_bf16(a0, a1);
        pc0 = x[xi0 + 2u * HW]; pc1 = x[xi1 + 2u * HW];   // x_2 (in flight)
    }
    __syncthreads();                                // xbuf = x_1; loop invariant
    unsigned toff = 0;

    __builtin_amdgcn_s_setprio(1);                  // chain priority default

    // invariant at step t entry: xbuf = x_{t+1}; pc = x_{t+2}; xzc = xz_t.
    auto step = [&](int t, float4v xzc, float4v& xzn,
                    float& c0, float& c1, float& n0, float& n1) {
        // issue loads of x_{t+3} (consumed at publish point of step t+1)
        const unsigned tl = (unsigned)((t + 3 < TSTEPS) ? t + 3 : TSTEPS - 1);
        if (xpr) { n0 = x[xi0 + tl * HW]; n1 = x[xi1 + tl * HW]; }

        // read x_{t+1} frag (before BAR A; publish happens after BAR A)
        unsigned xf[4];
        #pragma unroll
        for (int jj = 0; jj < 4; ++jj) xf[jj] = xbuf[xrow + jj][ln];

        // ---- phase 1 (prio 1): Z = hbuf verbatim; 2 MFMA; lecun; publish --
        unsigned h0 = hbuf[0][lane], h1 = hbuf[1][lane];
        unsigned h2 = hbuf[2][lane], h3 = hbuf[3][lane];
        uint4v zv = {h0, h1, h2, h3};
        bf16x8 Z = __builtin_bit_cast(bf16x8, zv);
        float4v a = mfma16(Whhi, Z, xzc);
        a = mfma16(Whlo, Z, a);
        float g0 = lecun_tanh_f(a[0]);
        float g1 = lecun_tanh_f(a[1]);
        float g2 = lecun_tanh_f(a[2]);
        float g3 = lecun_tanh_f(a[3]);
        abuf[mt * 2 + 0][lane] = cvt_pk_bf16(g0, g1);
        abuf[mt * 2 + 1][lane] = cvt_pk_bf16(g2, g3);
        BAR_LDS();                      // barrier A: acts published, x reads done

        // ---- filler (prio 0): publish x_{t+2}; compute xz_{t+1} ----
        __builtin_amdgcn_s_setprio(0);
        if (xpr) xbuf[xr][ln] = cvt_pk_bf16(c0, c1);
        {
            bf16x8 X = xfrag(xf);
            float4v q = mfma16(Wxhi, X, BBv);
            q = mfma16(Wxlo, X, q);
            xzn = q;
        }
        __builtin_amdgcn_s_setprio(1);

        // ---- assemble A2: frag kt = abuf rows 4kt..4kt+3 at own lane ----
        unsigned f0[4], f1[4];
        #pragma unroll
        for (int d = 0; d < 4; ++d) f0[d] = abuf[d][lane];
        #pragma unroll
        for (int d = 0; d < 4; ++d) f1[d] = abuf[4 + d][lane];
        uint4v w0 = {f0[0], f0[1], f0[2], f0[3]};
        uint4v w1 = {f1[0], f1[1], f1[2], f1[3]};
        bf16x8 A20 = __builtin_bit_cast(bf16x8, w0);
        bf16x8 A21 = __builtin_bit_cast(bf16x8, w1);

        // ---- phase 2: 2 head tiles, 2 MFMA each (hi only), gate, store ----
        float hn[2];
        #pragma unroll
        for (int i2 = 0; i2 < 2; ++i2) {
            float4v c = mfma16(Ah[i2][0], A20, HBv[i2]);
            c = mfma16(Ah[i2][1], A21, c);
            float f1g = tanh_f(c[0]);
            float f2g = tanh_f(c[1]);
            float ti  = sigmoid_f(c[2] + c[3]);
            float h   = fmaf(ti, f2g - f1g, f1g);
            out[oo[i2] + toff] = h;     // async store; never drained in loop
            hn[i2] = h;
        }
        hbuf[w][lane] = cvt_pk_bf16(hn[0], hn[1]);   // units (lq*8+2w, +1)
        BAR_LDS();                      // barrier B: h + x_{t+2} ready
        toff += (unsigned)HW;
    };

    #pragma unroll 1
    for (int t = 0; t < TSTEPS; t += 2) {
        step(t,     xzA, xzB, pc0, pc1, pn0, pn1);   // ping
        step(t + 1, xzB, xzA, pn0, pn1, pc0, pc1);   // pong (static, rule #20)
    }
}

extern "C" void kernel_launch(void* const* d_in, const int* in_sizes, int n_in,
                              void* d_out, int out_size, void* d_ws, size_t ws_size,
                              hipStream_t stream) {
    dim3 grid(4 * HW / NPIX);   // 1024 blocks x 4 waves -> 4 blocks/CU
    cfc_mfma_kernel<<<grid, NTHREADS, 0, stream>>>(
        (const float*)d_in[0], (const float*)d_in[1], (const float*)d_in[2],
        (const float*)d_in[3], (const float*)d_in[4], (const float*)d_in[5],
        (const float*)d_in[6], (const float*)d_in[7], (const float*)d_in[8],
        (const float*)d_in[9], (const float*)d_in[10],
        (float*)d_out);
}